// Round 1
// baseline (1628.378 us; speedup 1.0000x reference)
//
#include <hip/hip_runtime.h>

// FeedBack LSTM: B=1024, T_in=128, F=3, UNITS=256, out_steps=32.
// 64 persistent blocks x 512 threads; each block owns 16 batch rows (no
// inter-block communication needed: recurrence is per-row independent).
// h@Wr via mfma_f32_16x16x32_f16 (fp16 inputs, fp32 accum) for precision.

#define TIN     128
#define FIN     3
#define UNITS   256
#define OSTEPS  32
#define ROWS    16
#define NW      8
#define THREADS 512

typedef float    f32x4 __attribute__((ext_vector_type(4)));
typedef _Float16 half8 __attribute__((ext_vector_type(8)));

__device__ __forceinline__ float fast_rcp(float x) { return __builtin_amdgcn_rcpf(x); }
__device__ __forceinline__ float sigm(float x)  { return fast_rcp(1.0f + __expf(-x)); }
__device__ __forceinline__ float tanh_f(float x){ return 1.0f - 2.0f * fast_rcp(__expf(2.0f * x) + 1.0f); }

// Pack Wr [256][1024] fp32 -> B-fragment-ready fp16 layout:
// P[ct][kt][lane][j] = Wr[kt*32 + (lane>>4)*8 + j][ct*16 + (lane&15)]
// so each lane's B-frag for (col-tile ct, k-tile kt) is one 16B load.
__global__ __launch_bounds__(512) void pack_wr(const float* __restrict__ Wr,
                                               _Float16* __restrict__ P)
{
    int idx = blockIdx.x * 512 + threadIdx.x;   // (ct*8 + kt)*64 + lane, 32768 total
    int l   = idx & 63;
    int kt  = (idx >> 6) & 7;
    int ct  = idx >> 9;
    int g = l >> 4, n = l & 15;
    int col = ct * 16 + n;
    int k0  = kt * 32 + g * 8;
    half8 v;
#pragma unroll
    for (int j = 0; j < 8; ++j) v[j] = (_Float16)Wr[(k0 + j) * 1024 + col];
    *reinterpret_cast<half8*>(P + (size_t)idx * 8) = v;
}

__global__ __launch_bounds__(THREADS) void lstm_fused(
    const float* __restrict__ x_in,   // [1024][128][3]
    const float* __restrict__ Wk,     // [3][1024]
    const float* __restrict__ bias,   // [1024]
    const float* __restrict__ Wd,     // [256][3]
    const float* __restrict__ bd,     // [3]
    const _Float16* __restrict__ WrP, // packed Wr (fp16 fragments)
    float* __restrict__ out)          // [1024][32][3]
{
    // h in A-fragment order: hp[buf][kt*512 + lane*8 + j] = h[lane&15][kt*32+(lane>>4)*8+j]
    __shared__ alignas(16) _Float16 hp[2][8 * 64 * 8];        // 2 x 8 KB
    __shared__ alignas(16) float    xs_h[ROWS * TIN * FIN];   // 24 KB staged inputs
    __shared__ alignas(16) float    h_plain[ROWS][UNITS + 4]; // fp32 h rows (decode head)
    __shared__ float                pred_buf[ROWS][FIN];      // fed-back prediction

    const int tid  = threadIdx.x;
    const int w    = tid >> 6;     // wave 0..7: owns units [w*32, w*32+32) x 4 gates
    const int l    = tid & 63;
    const int g    = l >> 4;
    const int n    = l & 15;
    const int blk  = blockIdx.x;   // owns batch rows [blk*16, blk*16+16)
    const int row0 = g * 4;        // MFMA C-layout: this lane's rows row0..row0+3

    // ---- prologue: stage x, zero initial h, preload small weights ----
    const float* xsrc = x_in + (size_t)blk * ROWS * TIN * FIN;
    for (int i = tid; i < ROWS * TIN * FIN; i += THREADS) xs_h[i] = xsrc[i];
    for (int i = tid; i < 8 * 64 * 8; i += THREADS) hp[0][i] = (_Float16)0.0f;

    float wk_r[8][3], b_r[8];
    int   wboff[8];
#pragma unroll
    for (int q = 0; q < 8; ++q) {                 // q = gate*2 + sub
        int gate = q >> 1, sub = q & 1;
        int col  = gate * 256 + w * 32 + sub * 16 + n;
        b_r[q] = bias[col];
#pragma unroll
        for (int f = 0; f < 3; ++f) wk_r[q][f] = Wk[f * 1024 + col];
        int ct = gate * 16 + 2 * w + sub;
        wboff[q] = ct * 4096 + l * 8;             // element offset into WrP
    }
    float wd_r[4][3];
#pragma unroll
    for (int j = 0; j < 4; ++j)
#pragma unroll
        for (int f = 0; f < 3; ++f) wd_r[j][f] = Wd[(4 * l + j) * 3 + f];
    float bd_r[3];
#pragma unroll
    for (int f = 0; f < 3; ++f) bd_r[f] = bd[f];

    float c_st[2][4];
#pragma unroll
    for (int s = 0; s < 2; ++s)
#pragma unroll
        for (int r = 0; r < 4; ++r) c_st[s][r] = 0.0f;

    __syncthreads();

    int cur = 0;
    for (int t = 0; t < TIN + OSTEPS - 1; ++t) {  // 159 sequential cell steps
        const bool dec = (t >= TIN);

        // x for this step: staged input (warmup) or fed-back prediction (decode)
        float xv[4][3];
#pragma unroll
        for (int r = 0; r < 4; ++r) {
            int row = row0 + r;
            if (dec) {
                xv[r][0] = pred_buf[row][0];
                xv[r][1] = pred_buf[row][1];
                xv[r][2] = pred_buf[row][2];
            } else {
                const float* xp = &xs_h[(row * TIN + t) * 3];
                xv[r][0] = xp[0]; xv[r][1] = xp[1]; xv[r][2] = xp[2];
            }
        }

        // z init = b + x@Wk (fp32, in MFMA C-layout)
        f32x4 acc[8];
#pragma unroll
        for (int q = 0; q < 8; ++q)
#pragma unroll
            for (int r = 0; r < 4; ++r)
                acc[q][r] = b_r[q] + xv[r][0] * wk_r[q][0] + xv[r][1] * wk_r[q][1]
                          + xv[r][2] * wk_r[q][2];

        // z += h @ Wr : 8 k-tiles x 8 (gate,sub) tiles, 1-deep B-frag prefetch
        const _Float16* hpc = hp[cur];
        half8 bcur[8];
#pragma unroll
        for (int q = 0; q < 8; ++q)
            bcur[q] = *reinterpret_cast<const half8*>(WrP + wboff[q]);
#pragma unroll
        for (int kt = 0; kt < 8; ++kt) {
            half8 a = *reinterpret_cast<const half8*>(hpc + kt * 512 + l * 8);
            half8 bnxt[8];
            if (kt < 7) {
#pragma unroll
                for (int q = 0; q < 8; ++q)
                    bnxt[q] = *reinterpret_cast<const half8*>(WrP + wboff[q] + (kt + 1) * 512);
            }
#pragma unroll
            for (int q = 0; q < 8; ++q)
                acc[q] = __builtin_amdgcn_mfma_f32_16x16x32_f16(a, bcur[q], acc[q], 0, 0, 0);
            if (kt < 7) {
#pragma unroll
                for (int q = 0; q < 8; ++q) bcur[q] = bnxt[q];
            }
        }

        // gates + state update (fp32), write h for next step in A-frag order
        const int  nxt      = cur ^ 1;
        const bool wr_plain = (t >= TIN - 1);
#pragma unroll
        for (int sub = 0; sub < 2; ++sub) {
            int u    = w * 32 + sub * 16 + n;          // unit owned by this lane
            int kt   = u >> 5, gg = (u >> 3) & 3, j = u & 7;
            int base = kt * 512 + gg * 128 + j;
#pragma unroll
            for (int r = 0; r < 4; ++r) {
                float iv = sigm(acc[0 * 2 + sub][r]);
                float fv = sigm(acc[1 * 2 + sub][r]);
                float gv = tanh_f(acc[2 * 2 + sub][r]);
                float ov = sigm(acc[3 * 2 + sub][r]);
                float cc = fv * c_st[sub][r] + iv * gv;
                c_st[sub][r] = cc;
                float hv = ov * tanh_f(cc);
                int row  = row0 + r;
                hp[nxt][base + row * 8] = (_Float16)hv;
                if (wr_plain) h_plain[row][u] = hv;
            }
        }
        __syncthreads();

        // decode head: pred = h @ Wd + bd (fp32), wave w reduces rows 2w, 2w+1
        if (wr_plain) {
            int s = t - (TIN - 1);
#pragma unroll
            for (int rr = 0; rr < 2; ++rr) {
                int row = 2 * w + rr;
                const float4 hv4 = *reinterpret_cast<const float4*>(&h_plain[row][4 * l]);
                float p0 = hv4.x * wd_r[0][0] + hv4.y * wd_r[1][0] + hv4.z * wd_r[2][0] + hv4.w * wd_r[3][0];
                float p1 = hv4.x * wd_r[0][1] + hv4.y * wd_r[1][1] + hv4.z * wd_r[2][1] + hv4.w * wd_r[3][1];
                float p2 = hv4.x * wd_r[0][2] + hv4.y * wd_r[1][2] + hv4.z * wd_r[2][2] + hv4.w * wd_r[3][2];
#pragma unroll
                for (int off = 32; off > 0; off >>= 1) {
                    p0 += __shfl_xor(p0, off);
                    p1 += __shfl_xor(p1, off);
                    p2 += __shfl_xor(p2, off);
                }
                if (l == 0) {
                    float o0 = p0 + bd_r[0], o1 = p1 + bd_r[1], o2 = p2 + bd_r[2];
                    pred_buf[row][0] = o0; pred_buf[row][1] = o1; pred_buf[row][2] = o2;
                    float* op = out + (((size_t)blk * ROWS + row) * OSTEPS + s) * 3;
                    op[0] = o0; op[1] = o1; op[2] = o2;
                }
            }
            __syncthreads();
        }
        cur ^= 1;
    }
}

extern "C" void kernel_launch(void* const* d_in, const int* in_sizes, int n_in,
                              void* d_out, int out_size, void* d_ws, size_t ws_size,
                              hipStream_t stream)
{
    const float* x  = (const float*)d_in[0];
    const float* Wk = (const float*)d_in[1];
    const float* Wr = (const float*)d_in[2];
    const float* b  = (const float*)d_in[3];
    const float* Wd = (const float*)d_in[4];
    const float* bd = (const float*)d_in[5];
    _Float16* WrP = (_Float16*)d_ws;            // 512 KB packed recurrent weights
    float* out = (float*)d_out;

    pack_wr<<<64, 512, 0, stream>>>(Wr, WrP);
    lstm_fused<<<64, THREADS, 0, stream>>>(x, Wk, b, Wd, bd, WrP, out);
}